// Round 3
// baseline (1257.092 us; speedup 1.0000x reference)
//
#include <hip/hip_runtime.h>
#include <cstddef>
#include <math.h>

#define S_LEN  2048
#define HID_C  1024
#define NHEADS 16
#define HDIM   64

typedef __attribute__((ext_vector_type(8))) short bf16x8;
typedef __attribute__((ext_vector_type(4))) float f32x4;

// round-to-nearest-even fp32 -> bf16 (as raw ushort)
__device__ __forceinline__ unsigned short f32_to_bf16_rn(float f) {
    unsigned int u = __float_as_uint(f);
    u += 0x7FFFu + ((u >> 16) & 1u);
    return (unsigned short)(u >> 16);
}
__device__ __forceinline__ float bf16_to_f32(unsigned short h) {
    return __uint_as_float(((unsigned int)h) << 16);
}

// ---------------------------------------------------------------------------
// MFMA GEMM (bf16x3 split precision): out[m,n] = sum_k X[m,k]*W[n,k] + bias[n]
// X:[M,K] W:[N,K] row-major (X @ W^T shape == m97 gemm_bt: both operands load
// K-contiguous, lane&15 = m/n, 8 k-elems/lane).
// 128x128 tile, BK=32, 256 threads = 4 waves (2x2), 64x64 per wave.
// Split each fp32 into hi+lo bf16; acc += ah*bh + ah*bl + al*bh (fp32 MFMA acc).
// LDS rows padded to 40 bf16 (80B) -> fragment ds_read_b128 is 2-way (free).
// ---------------------------------------------------------------------------
#define BM 128
#define BN 128
#define BKg 32
#define LDK 40

__global__ __launch_bounds__(256) void gemm_xwt_bias_mfma(
    const float* __restrict__ X, const float* __restrict__ W,
    const float* __restrict__ bias, float* __restrict__ out,
    int M, int N, int K)
{
    __shared__ __align__(16) short Ah[BM * LDK];
    __shared__ __align__(16) short Al[BM * LDK];
    __shared__ __align__(16) short Bh[BM * LDK];
    __shared__ __align__(16) short Bl[BM * LDK];

    const int tid  = threadIdx.x;
    const int lane = tid & 63;
    const int wave = tid >> 6;
    const int bm = blockIdx.y * BM;
    const int bn = blockIdx.x * BN;
    const int wm = (wave >> 1) * 64;    // wave's M offset in tile
    const int wn = (wave & 1) * 64;     // wave's N offset in tile

    // stager: each thread owns row sr (0..127), k-halves sc (0 or 16)
    const int sr = tid >> 1;
    const int sc = (tid & 1) * 16;

    const float* Xp = X + (size_t)(bm + sr) * K + sc;
    const float* Wp = W + (size_t)(bn + sr) * K + sc;

    f32x4 acc[4][4];
#pragma unroll
    for (int i = 0; i < 4; ++i)
#pragma unroll
        for (int j = 0; j < 4; ++j)
#pragma unroll
            for (int r = 0; r < 4; ++r) acc[i][j][r] = 0.f;

    const int fr = lane & 15;           // fragment row (m) / col (n)
    const int kb = (lane >> 4) * 8;     // fragment k-base (elements)

    for (int k0 = 0; k0 < K; k0 += BKg) {
        // ---- issue global loads (overlaps prev-iter drain) ----
        float xv[16], wv[16];
#pragma unroll
        for (int q = 0; q < 4; ++q) {
            float4 a = *reinterpret_cast<const float4*>(Xp + k0 + q * 4);
            float4 b = *reinterpret_cast<const float4*>(Wp + k0 + q * 4);
            xv[q*4+0]=a.x; xv[q*4+1]=a.y; xv[q*4+2]=a.z; xv[q*4+3]=a.w;
            wv[q*4+0]=b.x; wv[q*4+1]=b.y; wv[q*4+2]=b.z; wv[q*4+3]=b.w;
        }
        __syncthreads();    // prev-iter LDS reads done

        // ---- split & stage ----
        short xh[16], xl[16], wh[16], wl[16];
#pragma unroll
        for (int j = 0; j < 16; ++j) {
            unsigned short h = f32_to_bf16_rn(xv[j]);
            xh[j] = (short)h;
            xl[j] = (short)f32_to_bf16_rn(xv[j] - bf16_to_f32(h));
            unsigned short g = f32_to_bf16_rn(wv[j]);
            wh[j] = (short)g;
            wl[j] = (short)f32_to_bf16_rn(wv[j] - bf16_to_f32(g));
        }
        const int wbase = sr * LDK + sc;
        *reinterpret_cast<bf16x8*>(&Ah[wbase])     = *reinterpret_cast<bf16x8*>(&xh[0]);
        *reinterpret_cast<bf16x8*>(&Ah[wbase + 8]) = *reinterpret_cast<bf16x8*>(&xh[8]);
        *reinterpret_cast<bf16x8*>(&Al[wbase])     = *reinterpret_cast<bf16x8*>(&xl[0]);
        *reinterpret_cast<bf16x8*>(&Al[wbase + 8]) = *reinterpret_cast<bf16x8*>(&xl[8]);
        *reinterpret_cast<bf16x8*>(&Bh[wbase])     = *reinterpret_cast<bf16x8*>(&wh[0]);
        *reinterpret_cast<bf16x8*>(&Bh[wbase + 8]) = *reinterpret_cast<bf16x8*>(&wh[8]);
        *reinterpret_cast<bf16x8*>(&Bl[wbase])     = *reinterpret_cast<bf16x8*>(&wl[0]);
        *reinterpret_cast<bf16x8*>(&Bl[wbase + 8]) = *reinterpret_cast<bf16x8*>(&wl[8]);
        __syncthreads();

        // ---- fragment loads ----
        bf16x8 fah[4], fal[4], fbh[4], fbl[4];
#pragma unroll
        for (int mi = 0; mi < 4; ++mi) {
            const int ra = (wm + mi * 16 + fr) * LDK + kb;
            fah[mi] = *reinterpret_cast<const bf16x8*>(&Ah[ra]);
            fal[mi] = *reinterpret_cast<const bf16x8*>(&Al[ra]);
        }
#pragma unroll
        for (int ni = 0; ni < 4; ++ni) {
            const int rb = (wn + ni * 16 + fr) * LDK + kb;
            fbh[ni] = *reinterpret_cast<const bf16x8*>(&Bh[rb]);
            fbl[ni] = *reinterpret_cast<const bf16x8*>(&Bl[rb]);
        }

        // ---- MFMA: acc += ah*bh + ah*bl + al*bh ----
#pragma unroll
        for (int mi = 0; mi < 4; ++mi)
#pragma unroll
            for (int ni = 0; ni < 4; ++ni) {
                acc[mi][ni] = __builtin_amdgcn_mfma_f32_16x16x32_bf16(
                    fah[mi], fbh[ni], acc[mi][ni], 0, 0, 0);
                acc[mi][ni] = __builtin_amdgcn_mfma_f32_16x16x32_bf16(
                    fah[mi], fbl[ni], acc[mi][ni], 0, 0, 0);
                acc[mi][ni] = __builtin_amdgcn_mfma_f32_16x16x32_bf16(
                    fal[mi], fbh[ni], acc[mi][ni], 0, 0, 0);
            }
    }

    // ---- epilogue: C/D layout col=lane&15, row=(lane>>4)*4+r ----
    const int fq = lane >> 4;
    float bv[4];
#pragma unroll
    for (int ni = 0; ni < 4; ++ni) bv[ni] = bias[bn + wn + ni * 16 + fr];
#pragma unroll
    for (int mi = 0; mi < 4; ++mi)
#pragma unroll
        for (int ni = 0; ni < 4; ++ni) {
            const size_t rowb = (size_t)(bm + wm + mi * 16 + fq * 4);
            const int col = bn + wn + ni * 16 + fr;
#pragma unroll
            for (int r = 0; r < 4; ++r)
                out[(rowb + r) * N + col] = acc[mi][ni][r] + bv[ni];
        }
}

// ---------------------------------------------------------------------------
// Flash attention fp32 (unchanged correctness anchor). One block = one
// (b, h, 64-row Q tile). TK = 64. energy = QK^T/8, mask==0 -> -1e10,
// online softmax, O = P V.
// ---------------------------------------------------------------------------
__global__ __launch_bounds__(256) void flash_attn_f32(
    const float* __restrict__ Q, const float* __restrict__ K,
    const float* __restrict__ V, const int* __restrict__ mask,
    float* __restrict__ Xout)
{
    __shared__ float Qs[64][68];
    __shared__ float Kt[64][64];
    __shared__ float Vs[64][68];
    __shared__ float Ps[64][68];

    const int b  = blockIdx.y >> 4;
    const int h  = blockIdx.y & 15;
    const int q0 = blockIdx.x << 6;
    const int tid = threadIdx.x;
    const int rg = tid >> 4;
    const int kg = tid & 15;
    const int lr = tid >> 2;
    const int lc = (tid & 3) << 4;

    const size_t bS = (size_t)b * S_LEN;
    const float* Qg = Q + (bS + q0) * HID_C + (size_t)h * HDIM;
    const float* Kg = K + bS * HID_C + (size_t)h * HDIM;
    const float* Vg = V + bS * HID_C + (size_t)h * HDIM;

    {
        const float* src = Qg + (size_t)lr * HID_C + lc;
#pragma unroll
        for (int c = 0; c < 16; c += 4) {
            float4 v = *reinterpret_cast<const float4*>(src + c);
            *reinterpret_cast<float4*>(&Qs[lr][lc + c]) = v;
        }
    }

    float m_[4], l_[4], o_[4][4];
#pragma unroll
    for (int i = 0; i < 4; ++i) {
        m_[i] = -INFINITY; l_[i] = 0.f;
#pragma unroll
        for (int j = 0; j < 4; ++j) o_[i][j] = 0.f;
    }

    for (int t = 0; t < S_LEN; t += 64) {
        __syncthreads();
        {
            const float* ks = Kg + (size_t)(t + lr) * HID_C + lc;
            const float* vs = Vg + (size_t)(t + lr) * HID_C + lc;
#pragma unroll
            for (int c = 0; c < 16; c += 4) {
                float4 kv = *reinterpret_cast<const float4*>(ks + c);
                Kt[lc + c + 0][lr] = kv.x;
                Kt[lc + c + 1][lr] = kv.y;
                Kt[lc + c + 2][lr] = kv.z;
                Kt[lc + c + 3][lr] = kv.w;
                float4 vv = *reinterpret_cast<const float4*>(vs + c);
                *reinterpret_cast<float4*>(&Vs[lr][lc + c]) = vv;
            }
        }
        __syncthreads();

        float s_[4][4];
#pragma unroll
        for (int i = 0; i < 4; ++i)
#pragma unroll
            for (int j = 0; j < 4; ++j) s_[i][j] = 0.f;

        for (int d0 = 0; d0 < HDIM; d0 += 4) {
            float q[4][4], kf[4][4];
#pragma unroll
            for (int i = 0; i < 4; ++i) {
                float4 v = *reinterpret_cast<const float4*>(&Qs[rg * 4 + i][d0]);
                q[i][0] = v.x; q[i][1] = v.y; q[i][2] = v.z; q[i][3] = v.w;
            }
#pragma unroll
            for (int dd = 0; dd < 4; ++dd) {
                float4 v = *reinterpret_cast<const float4*>(&Kt[d0 + dd][kg * 4]);
                kf[dd][0] = v.x; kf[dd][1] = v.y; kf[dd][2] = v.z; kf[dd][3] = v.w;
            }
#pragma unroll
            for (int dd = 0; dd < 4; ++dd)
#pragma unroll
                for (int i = 0; i < 4; ++i)
#pragma unroll
                    for (int j = 0; j < 4; ++j)
                        s_[i][j] = fmaf(q[i][dd], kf[dd][j], s_[i][j]);
        }

        int mk[4];
#pragma unroll
        for (int j = 0; j < 4; ++j) mk[j] = mask[bS + t + kg * 4 + j];
#pragma unroll
        for (int i = 0; i < 4; ++i)
#pragma unroll
            for (int j = 0; j < 4; ++j)
                s_[i][j] = (mk[j] != 0) ? s_[i][j] * 0.125f : -1e10f;

        float mx[4];
#pragma unroll
        for (int i = 0; i < 4; ++i)
            mx[i] = fmaxf(fmaxf(s_[i][0], s_[i][1]), fmaxf(s_[i][2], s_[i][3]));
#pragma unroll
        for (int off = 1; off < 16; off <<= 1)
#pragma unroll
            for (int i = 0; i < 4; ++i)
                mx[i] = fmaxf(mx[i], __shfl_xor(mx[i], off));

        float corr[4], ls[4];
#pragma unroll
        for (int i = 0; i < 4; ++i) {
            float mn = fmaxf(m_[i], mx[i]);
            corr[i] = __expf(m_[i] - mn);
            m_[i] = mn;
            ls[i] = 0.f;
        }
#pragma unroll
        for (int i = 0; i < 4; ++i)
#pragma unroll
            for (int j = 0; j < 4; ++j) {
                float p = __expf(s_[i][j] - m_[i]);
                Ps[rg * 4 + i][kg * 4 + j] = p;
                ls[i] += p;
            }
#pragma unroll
        for (int off = 1; off < 16; off <<= 1)
#pragma unroll
            for (int i = 0; i < 4; ++i)
                ls[i] += __shfl_xor(ls[i], off);
#pragma unroll
        for (int i = 0; i < 4; ++i) {
            l_[i] = l_[i] * corr[i] + ls[i];
#pragma unroll
            for (int j = 0; j < 4; ++j) o_[i][j] *= corr[i];
        }

        for (int ki = 0; ki < 64; ++ki) {
            float4 v4 = *reinterpret_cast<const float4*>(&Vs[ki][kg * 4]);
#pragma unroll
            for (int i = 0; i < 4; ++i) {
                float pv = Ps[rg * 4 + i][ki];
                o_[i][0] = fmaf(pv, v4.x, o_[i][0]);
                o_[i][1] = fmaf(pv, v4.y, o_[i][1]);
                o_[i][2] = fmaf(pv, v4.z, o_[i][2]);
                o_[i][3] = fmaf(pv, v4.w, o_[i][3]);
            }
        }
    }

#pragma unroll
    for (int i = 0; i < 4; ++i) {
        float inv = 1.f / l_[i];
        float4 o4;
        o4.x = o_[i][0] * inv; o4.y = o_[i][1] * inv;
        o4.z = o_[i][2] * inv; o4.w = o_[i][3] * inv;
        *reinterpret_cast<float4*>(
            &Xout[(bS + q0 + rg * 4 + i) * HID_C + (size_t)h * HDIM + kg * 4]) = o4;
    }
}

// ---------------------------------------------------------------------------
extern "C" void kernel_launch(void* const* d_in, const int* in_sizes, int n_in,
                              void* d_out, int out_size, void* d_ws, size_t ws_size,
                              hipStream_t stream) {
    const float* query = (const float*)d_in[0];
    const float* key   = (const float*)d_in[1];
    const float* value = (const float*)d_in[2];
    const int*   mask  = (const int*)d_in[3];
    const float* Wq = (const float*)d_in[4];
    const float* bq = (const float*)d_in[5];
    const float* Wk = (const float*)d_in[6];
    const float* bk = (const float*)d_in[7];
    const float* Wv = (const float*)d_in[8];
    const float* bv = (const float*)d_in[9];
    const float* Wo = (const float*)d_in[10];
    const float* bo = (const float*)d_in[11];
    float* out = (float*)d_out;

    const int B = 4, M = B * S_LEN;          // 8192
    const size_t seg = (size_t)M * HID_C;    // floats per [B,S,HID] tensor

    float* Qw = (float*)d_ws;
    float* Kw = Qw + seg;
    float* Vw = Kw + seg;
    float* Xw = Vw + seg;                    // 128 MB of ws total

    dim3 gg(HID_C / BN, M / BM);             // (8, 64)
    gemm_xwt_bias_mfma<<<gg, 256, 0, stream>>>(query, Wq, bq, Qw, M, HID_C, HID_C);
    gemm_xwt_bias_mfma<<<gg, 256, 0, stream>>>(key,   Wk, bk, Kw, M, HID_C, HID_C);
    gemm_xwt_bias_mfma<<<gg, 256, 0, stream>>>(value, Wv, bv, Vw, M, HID_C, HID_C);

    dim3 ga(S_LEN / 64, B * NHEADS);         // (32, 64)
    flash_attn_f32<<<ga, 256, 0, stream>>>(Qw, Kw, Vw, mask, Xw);

    gemm_xwt_bias_mfma<<<gg, 256, 0, stream>>>(Xw, Wo, bo, out, M, HID_C, HID_C);
}

// Round 4
// 536.907 us; speedup vs baseline: 2.3414x; 2.3414x over previous
//
#include <hip/hip_runtime.h>
#include <cstddef>
#include <math.h>

#define S_LEN  2048
#define HID_C  1024
#define NHEADS 16
#define HDIM   64

typedef __attribute__((ext_vector_type(8))) short bf16x8;
typedef __attribute__((ext_vector_type(4))) float f32x4;
typedef unsigned short ushort_t;

// round-to-nearest-even fp32 -> bf16 (raw ushort)
__device__ __forceinline__ unsigned short f32_to_bf16_rn(float f) {
    unsigned int u = __float_as_uint(f);
    u += 0x7FFFu + ((u >> 16) & 1u);
    return (unsigned short)(u >> 16);
}
__device__ __forceinline__ float bf16_to_f32(unsigned short h) {
    return __uint_as_float(((unsigned int)h) << 16);
}

// ---------------------------------------------------------------------------
// MFMA GEMM (bf16x3 split precision): out[m,n] = sum_k X[m,k]*W[n,k] + bias[n]
// OMODE 0: write fp32 out.  OMODE 1: write bf16 out (for Q/K/V feeding attn).
// 128x128 tile, BK=32, 4 waves (2x2), 64x64/wave. LDS rows 40 shorts (80B).
// ---------------------------------------------------------------------------
#define BM 128
#define BN 128
#define BKg 32
#define LDKg 40

template <int OMODE>
__global__ __launch_bounds__(256) void gemm_xwt_bias_mfma(
    const float* __restrict__ X, const float* __restrict__ W,
    const float* __restrict__ bias, float* __restrict__ outF,
    ushort_t* __restrict__ outB, int M, int N, int K)
{
    __shared__ __align__(16) short Ah[BM * LDKg];
    __shared__ __align__(16) short Al[BM * LDKg];
    __shared__ __align__(16) short Bh[BM * LDKg];
    __shared__ __align__(16) short Bl[BM * LDKg];

    const int tid  = threadIdx.x;
    const int lane = tid & 63;
    const int wave = tid >> 6;
    const int bm = blockIdx.y * BM;
    const int bn = blockIdx.x * BN;
    const int wm = (wave >> 1) * 64;
    const int wn = (wave & 1) * 64;

    const int sr = tid >> 1;
    const int sc = (tid & 1) * 16;

    const float* Xp = X + (size_t)(bm + sr) * K + sc;
    const float* Wp = W + (size_t)(bn + sr) * K + sc;

    f32x4 acc[4][4];
#pragma unroll
    for (int i = 0; i < 4; ++i)
#pragma unroll
        for (int j = 0; j < 4; ++j)
#pragma unroll
            for (int r = 0; r < 4; ++r) acc[i][j][r] = 0.f;

    const int fr = lane & 15;
    const int kb = (lane >> 4) * 8;

    for (int k0 = 0; k0 < K; k0 += BKg) {
        float xv[16], wv[16];
#pragma unroll
        for (int q = 0; q < 4; ++q) {
            float4 a = *reinterpret_cast<const float4*>(Xp + k0 + q * 4);
            float4 b = *reinterpret_cast<const float4*>(Wp + k0 + q * 4);
            xv[q*4+0]=a.x; xv[q*4+1]=a.y; xv[q*4+2]=a.z; xv[q*4+3]=a.w;
            wv[q*4+0]=b.x; wv[q*4+1]=b.y; wv[q*4+2]=b.z; wv[q*4+3]=b.w;
        }
        __syncthreads();

        short xh[16], xl[16], wh[16], wl[16];
#pragma unroll
        for (int j = 0; j < 16; ++j) {
            unsigned short h = f32_to_bf16_rn(xv[j]);
            xh[j] = (short)h;
            xl[j] = (short)f32_to_bf16_rn(xv[j] - bf16_to_f32(h));
            unsigned short g = f32_to_bf16_rn(wv[j]);
            wh[j] = (short)g;
            wl[j] = (short)f32_to_bf16_rn(wv[j] - bf16_to_f32(g));
        }
        const int wbase = sr * LDKg + sc;
        *reinterpret_cast<bf16x8*>(&Ah[wbase])     = *reinterpret_cast<bf16x8*>(&xh[0]);
        *reinterpret_cast<bf16x8*>(&Ah[wbase + 8]) = *reinterpret_cast<bf16x8*>(&xh[8]);
        *reinterpret_cast<bf16x8*>(&Al[wbase])     = *reinterpret_cast<bf16x8*>(&xl[0]);
        *reinterpret_cast<bf16x8*>(&Al[wbase + 8]) = *reinterpret_cast<bf16x8*>(&xl[8]);
        *reinterpret_cast<bf16x8*>(&Bh[wbase])     = *reinterpret_cast<bf16x8*>(&wh[0]);
        *reinterpret_cast<bf16x8*>(&Bh[wbase + 8]) = *reinterpret_cast<bf16x8*>(&wh[8]);
        *reinterpret_cast<bf16x8*>(&Bl[wbase])     = *reinterpret_cast<bf16x8*>(&wl[0]);
        *reinterpret_cast<bf16x8*>(&Bl[wbase + 8]) = *reinterpret_cast<bf16x8*>(&wl[8]);
        __syncthreads();

        bf16x8 fah[4], fal[4], fbh[4], fbl[4];
#pragma unroll
        for (int mi = 0; mi < 4; ++mi) {
            const int ra = (wm + mi * 16 + fr) * LDKg + kb;
            fah[mi] = *reinterpret_cast<const bf16x8*>(&Ah[ra]);
            fal[mi] = *reinterpret_cast<const bf16x8*>(&Al[ra]);
        }
#pragma unroll
        for (int ni = 0; ni < 4; ++ni) {
            const int rb = (wn + ni * 16 + fr) * LDKg + kb;
            fbh[ni] = *reinterpret_cast<const bf16x8*>(&Bh[rb]);
            fbl[ni] = *reinterpret_cast<const bf16x8*>(&Bl[rb]);
        }

#pragma unroll
        for (int mi = 0; mi < 4; ++mi)
#pragma unroll
            for (int ni = 0; ni < 4; ++ni) {
                acc[mi][ni] = __builtin_amdgcn_mfma_f32_16x16x32_bf16(
                    fah[mi], fbh[ni], acc[mi][ni], 0, 0, 0);
                acc[mi][ni] = __builtin_amdgcn_mfma_f32_16x16x32_bf16(
                    fah[mi], fbl[ni], acc[mi][ni], 0, 0, 0);
                acc[mi][ni] = __builtin_amdgcn_mfma_f32_16x16x32_bf16(
                    fal[mi], fbh[ni], acc[mi][ni], 0, 0, 0);
            }
    }

    const int fq = lane >> 4;
    float bv[4];
#pragma unroll
    for (int ni = 0; ni < 4; ++ni) bv[ni] = bias[bn + wn + ni * 16 + fr];
#pragma unroll
    for (int mi = 0; mi < 4; ++mi)
#pragma unroll
        for (int ni = 0; ni < 4; ++ni) {
            const size_t rowb = (size_t)(bm + wm + mi * 16 + fq * 4);
            const int col = bn + wn + ni * 16 + fr;
#pragma unroll
            for (int r = 0; r < 4; ++r) {
                float v = acc[mi][ni][r] + bv[ni];
                if (OMODE == 0) outF[(rowb + r) * N + col] = v;
                else            outB[(rowb + r) * N + col] = f32_to_bf16_rn(v);
            }
        }
}

// ---------------------------------------------------------------------------
// Flash attention, bf16 MFMA. One block = (b, h, 128-row Q tile); 4 waves,
// wave w owns q-rows [w*32, w*32+32). KVBLK=64.
// K LDS: [k][72] row-major (uniform-bank b128 frag reads).
// V LDS: transposed [d][72] with XOR swizzle idx = d*72 + (k ^ (d&48))
//        (write & read use the same involution -> conflict-free transpose).
// P: computed in C/D layout, round-trips via wave-private LDS rows -> A-frags.
// ---------------------------------------------------------------------------
#define QBLK 128
#define KVB  64
#define LDA  72   // shorts per row (144B: uniform 8-slot bank spread)

__global__ __launch_bounds__(256) void flash_attn_bf16(
    const ushort_t* __restrict__ Qb, const ushort_t* __restrict__ Kb,
    const ushort_t* __restrict__ Vb, const int* __restrict__ mask,
    float* __restrict__ Xout)
{
    __shared__ __align__(16) ushort_t Ks[KVB * LDA];
    __shared__ __align__(16) ushort_t Vt[HDIM * LDA];
    __shared__ __align__(16) ushort_t Ps[QBLK * LDA];

    const int b  = blockIdx.y >> 4;
    const int h  = blockIdx.y & 15;
    const int q0 = blockIdx.x * QBLK;
    const int tid  = threadIdx.x;
    const int lane = tid & 63;
    const int w    = tid >> 6;
    const int fr = lane & 15;
    const int fq = lane >> 4;

    const size_t bS = (size_t)b * S_LEN;
    const int hc = h * HDIM;

    // Q fragments in registers: wave w rows q0 + w*32 + mt*16 + fr
    bf16x8 qf[2][2];
#pragma unroll
    for (int mt = 0; mt < 2; ++mt)
#pragma unroll
        for (int c = 0; c < 2; ++c)
            qf[mt][c] = *reinterpret_cast<const bf16x8*>(
                &Qb[(bS + q0 + w * 32 + mt * 16 + fr) * HID_C + hc + c * 32 + fq * 8]);

    f32x4 OV[2][4];
    float m_[8], l_[8];
#pragma unroll
    for (int mt = 0; mt < 2; ++mt)
#pragma unroll
        for (int dt = 0; dt < 4; ++dt)
#pragma unroll
            for (int r = 0; r < 4; ++r) OV[mt][dt][r] = 0.f;
#pragma unroll
    for (int i = 0; i < 8; ++i) { m_[i] = -INFINITY; l_[i] = 0.f; }

    // stager mapping: r = tid>>2 (k-row 0..63), seg = tid&3 (16-short chunk)
    const int sr  = tid >> 2;
    const int seg = tid & 3;

    for (int t = 0; t < S_LEN; t += KVB) {
        // ---- global loads (issue before barrier) ----
        const ushort_t* kp = &Kb[(bS + t + sr) * HID_C + hc + seg * 16];
        const ushort_t* vp = &Vb[(bS + t + sr) * HID_C + hc + seg * 16];
        bf16x8 kv0 = *reinterpret_cast<const bf16x8*>(kp);
        bf16x8 kv1 = *reinterpret_cast<const bf16x8*>(kp + 8);
        bf16x8 vv0 = *reinterpret_cast<const bf16x8*>(vp);
        bf16x8 vv1 = *reinterpret_cast<const bf16x8*>(vp + 8);

        __syncthreads();   // prev-iter LDS reads done

        // K rows: [k][d], row stride 72 shorts
        *reinterpret_cast<bf16x8*>(&Ks[sr * LDA + seg * 16])     = kv0;
        *reinterpret_cast<bf16x8*>(&Ks[sr * LDA + seg * 16 + 8]) = kv1;
        // V transpose with XOR swizzle: elem (d, k=sr) -> Vt[d*72 + (sr ^ (d&48))]
        // d = seg*16 + j  (j<16 -> d&48 == seg*16)
        {
            const int swz = sr ^ (seg * 16);
#pragma unroll
            for (int j = 0; j < 8; ++j)
                Vt[(seg * 16 + j) * LDA + swz] = (ushort_t)vv0[j];
#pragma unroll
            for (int j = 0; j < 8; ++j)
                Vt[(seg * 16 + 8 + j) * LDA + swz] = (ushort_t)vv1[j];
        }
        __syncthreads();

        // ---- mask for this tile's k-columns ----
        int mk[4];
#pragma unroll
        for (int nt = 0; nt < 4; ++nt) mk[nt] = mask[bS + t + nt * 16 + fr];

        // ---- QK^T: S[mt][nt], q=w*32+mt*16+(fq*4+rr), k=nt*16+fr ----
        f32x4 S[2][4];
#pragma unroll
        for (int mt = 0; mt < 2; ++mt)
#pragma unroll
            for (int nt = 0; nt < 4; ++nt)
#pragma unroll
                for (int r = 0; r < 4; ++r) S[mt][nt][r] = 0.f;

#pragma unroll
        for (int nt = 0; nt < 4; ++nt)
#pragma unroll
            for (int c = 0; c < 2; ++c) {
                bf16x8 kf = *reinterpret_cast<const bf16x8*>(
                    &Ks[(nt * 16 + fr) * LDA + c * 32 + fq * 8]);
#pragma unroll
                for (int mt = 0; mt < 2; ++mt)
                    S[mt][nt] = __builtin_amdgcn_mfma_f32_16x16x32_bf16(
                        qf[mt][c], kf, S[mt][nt], 0, 0, 0);
            }

        // ---- scale + mask + online softmax ----
#pragma unroll
        for (int mt = 0; mt < 2; ++mt)
#pragma unroll
            for (int nt = 0; nt < 4; ++nt)
#pragma unroll
                for (int r = 0; r < 4; ++r)
                    S[mt][nt][r] = (mk[nt] != 0) ? S[mt][nt][r] * 0.125f : -1e10f;

#pragma unroll
        for (int mt = 0; mt < 2; ++mt)
#pragma unroll
            for (int r = 0; r < 4; ++r) {
                const int qi = mt * 4 + r;
                float mx = fmaxf(fmaxf(S[mt][0][r], S[mt][1][r]),
                                 fmaxf(S[mt][2][r], S[mt][3][r]));
                mx = fmaxf(mx, __shfl_xor(mx, 1));
                mx = fmaxf(mx, __shfl_xor(mx, 2));
                mx = fmaxf(mx, __shfl_xor(mx, 4));
                mx = fmaxf(mx, __shfl_xor(mx, 8));
                float mn = fmaxf(m_[qi], mx);
                float corr = __expf(m_[qi] - mn);
                m_[qi] = mn;
                float ls = 0.f;
#pragma unroll
                for (int nt = 0; nt < 4; ++nt) {
                    float p = __expf(S[mt][nt][r] - mn);
                    S[mt][nt][r] = p;
                    ls += p;
                }
                ls += __shfl_xor(ls, 1);
                ls += __shfl_xor(ls, 2);
                ls += __shfl_xor(ls, 4);
                ls += __shfl_xor(ls, 8);
                l_[qi] = l_[qi] * corr + ls;
#pragma unroll
                for (int dt = 0; dt < 4; ++dt) OV[mt][dt][r] *= corr;
            }

        // ---- P -> wave-private LDS rows (C/D layout -> A-frag layout) ----
#pragma unroll
        for (int mt = 0; mt < 2; ++mt)
#pragma unroll
            for (int nt = 0; nt < 4; ++nt)
#pragma unroll
                for (int r = 0; r < 4; ++r)
                    Ps[(w * 32 + mt * 16 + fq * 4 + r) * LDA + nt * 16 + fr] =
                        f32_to_bf16_rn(S[mt][nt][r]);
        // wave-private region: writer == reader wave, no barrier needed.

        // ---- PV: OV[mt][dt] += P[mt] @ V,  B-frag = Vt row d, k-contig ----
        bf16x8 pf[2][2];
#pragma unroll
        for (int mt = 0; mt < 2; ++mt)
#pragma unroll
            for (int c = 0; c < 2; ++c)
                pf[mt][c] = *reinterpret_cast<const bf16x8*>(
                    &Ps[(w * 32 + mt * 16 + fr) * LDA + c * 32 + fq * 8]);

#pragma unroll
        for (int dt = 0; dt < 4; ++dt)
#pragma unroll
            for (int c = 0; c < 2; ++c) {
                bf16x8 vf = *reinterpret_cast<const bf16x8*>(
                    &Vt[(dt * 16 + fr) * LDA + ((c * 32 + fq * 8) ^ (dt * 16))]);
#pragma unroll
                for (int mt = 0; mt < 2; ++mt)
                    OV[mt][dt] = __builtin_amdgcn_mfma_f32_16x16x32_bf16(
                        pf[mt][c], vf, OV[mt][dt], 0, 0, 0);
            }
    }

    // ---- epilogue: x[q][d] = OV / l ----
#pragma unroll
    for (int mt = 0; mt < 2; ++mt)
#pragma unroll
        for (int r = 0; r < 4; ++r) {
            const float inv = 1.f / l_[mt * 4 + r];
            const size_t row = bS + q0 + w * 32 + mt * 16 + fq * 4 + r;
#pragma unroll
            for (int dt = 0; dt < 4; ++dt)
                Xout[row * HID_C + hc + dt * 16 + fr] = OV[mt][dt][r] * inv;
        }
}

// ---------------------------------------------------------------------------
extern "C" void kernel_launch(void* const* d_in, const int* in_sizes, int n_in,
                              void* d_out, int out_size, void* d_ws, size_t ws_size,
                              hipStream_t stream) {
    const float* query = (const float*)d_in[0];
    const float* key   = (const float*)d_in[1];
    const float* value = (const float*)d_in[2];
    const int*   mask  = (const int*)d_in[3];
    const float* Wq = (const float*)d_in[4];
    const float* bq = (const float*)d_in[5];
    const float* Wk = (const float*)d_in[6];
    const float* bk = (const float*)d_in[7];
    const float* Wv = (const float*)d_in[8];
    const float* bv = (const float*)d_in[9];
    const float* Wo = (const float*)d_in[10];
    const float* bo = (const float*)d_in[11];
    float* out = (float*)d_out;

    const int B = 4, M = B * S_LEN;          // 8192
    const size_t seg = (size_t)M * HID_C;    // elements per [B,S,HID] tensor

    ushort_t* Qb = (ushort_t*)d_ws;          // bf16 Q/K/V: 16MB each
    ushort_t* Kb = Qb + seg;
    ushort_t* Vb = Kb + seg;
    float*    Xw = (float*)(Vb + seg);       // fp32 attn output: 32MB (total 80MB)

    dim3 gg(HID_C / BN, M / BM);             // (8, 64)
    gemm_xwt_bias_mfma<1><<<gg, 256, 0, stream>>>(query, Wq, bq, nullptr, Qb, M, HID_C, HID_C);
    gemm_xwt_bias_mfma<1><<<gg, 256, 0, stream>>>(key,   Wk, bk, nullptr, Kb, M, HID_C, HID_C);
    gemm_xwt_bias_mfma<1><<<gg, 256, 0, stream>>>(value, Wv, bv, nullptr, Vb, M, HID_C, HID_C);

    dim3 ga(S_LEN / QBLK, B * NHEADS);       // (16, 64)
    flash_attn_bf16<<<ga, 256, 0, stream>>>(Qb, Kb, Vb, mask, Xw);

    gemm_xwt_bias_mfma<0><<<gg, 256, 0, stream>>>(Xw, Wo, bo, out, nullptr, M, HID_C, HID_C);
}

// Round 5
// 448.459 us; speedup vs baseline: 2.8031x; 1.1972x over previous
//
#include <hip/hip_runtime.h>
#include <cstddef>
#include <math.h>

#define S_LEN  2048
#define HID_C  1024
#define NHEADS 16
#define HDIM   64

typedef __attribute__((ext_vector_type(8))) short bf16x8;
typedef __attribute__((ext_vector_type(4))) float f32x4;
typedef unsigned short ushort_t;

#define LOG2E 1.44269504088896f

// cheap round-to-nearest fp32 -> bf16 (ties-up; same 1/2-ulp bound as RNE)
__device__ __forceinline__ unsigned short f32_to_bf16_rn(float f) {
    unsigned int u = __float_as_uint(f);
    return (unsigned short)((u + 0x8000u) >> 16);
}
__device__ __forceinline__ float bf16_to_f32(unsigned short h) {
    return __uint_as_float(((unsigned int)h) << 16);
}

// ---------------------------------------------------------------------------
// MFMA GEMM, split-A: out[m,n] = sum_k X[m,k]*W[n,k] + bias
//   A = X split into hi+lo bf16 (either from fp32 on the fly, or pre-split),
//   B = W rounded to bf16.  acc += xh*wh + xl*wh.
// OMODE 0: fp32 out, col bias.  OMODE 1: bf16 out, col bias.
// OMODE 2: bf16 out, ROW bias (used for the swapped V^T GEMM).
// ASPLIT 0: Xf fp32 source.   ASPLIT 1: Xhi/Xlo pre-split bf16 source.
// 128x128 tile, BK=32, 4 waves (2x2), 64x64/wave. LDS rows 40 shorts (80B).
// ---------------------------------------------------------------------------
#define BM 128
#define BN 128
#define BKg 32
#define LDKg 40

template <int OMODE, int ASPLIT>
__global__ __launch_bounds__(256) void gemm_xwt_bias_mfma(
    const float* __restrict__ Xf,
    const ushort_t* __restrict__ Xhi, const ushort_t* __restrict__ Xlo,
    const float* __restrict__ W, const float* __restrict__ bias,
    float* __restrict__ outF, ushort_t* __restrict__ outB,
    int M, int N, int K)
{
    __shared__ __align__(16) short Ah[BM * LDKg];
    __shared__ __align__(16) short Al[BM * LDKg];
    __shared__ __align__(16) short Bh[BM * LDKg];

    const int tid  = threadIdx.x;
    const int lane = tid & 63;
    const int wave = tid >> 6;
    const int bm = blockIdx.y * BM;
    const int bn = blockIdx.x * BN;
    const int wm = (wave >> 1) * 64;
    const int wn = (wave & 1) * 64;

    const int sr = tid >> 1;
    const int sc = (tid & 1) * 16;

    const float* Wp = W + (size_t)(bn + sr) * K + sc;

    f32x4 acc[4][4];
#pragma unroll
    for (int i = 0; i < 4; ++i)
#pragma unroll
        for (int j = 0; j < 4; ++j)
#pragma unroll
            for (int r = 0; r < 4; ++r) acc[i][j][r] = 0.f;

    const int fr = lane & 15;
    const int kb = (lane >> 4) * 8;

    for (int k0 = 0; k0 < K; k0 += BKg) {
        // ---- load & prep A (hi/lo) and W (hi) ----
        short xh[16], xl[16], wh[16];
        if (ASPLIT == 0) {
            const float* Xp = Xf + (size_t)(bm + sr) * K + sc + k0;
            float xv[16];
#pragma unroll
            for (int q = 0; q < 4; ++q) {
                float4 a = *reinterpret_cast<const float4*>(Xp + q * 4);
                xv[q*4+0]=a.x; xv[q*4+1]=a.y; xv[q*4+2]=a.z; xv[q*4+3]=a.w;
            }
#pragma unroll
            for (int j = 0; j < 16; ++j) {
                unsigned int u = __float_as_uint(xv[j]);
                xh[j] = (short)(u >> 16);                       // trunc hi
                float res = xv[j] - __uint_as_float(u & 0xFFFF0000u);
                xl[j] = (short)f32_to_bf16_rn(res);
            }
        } else {
            const ushort_t* hp = Xhi + (size_t)(bm + sr) * K + sc + k0;
            const ushort_t* lp = Xlo + (size_t)(bm + sr) * K + sc + k0;
            *reinterpret_cast<bf16x8*>(&xh[0]) = *reinterpret_cast<const bf16x8*>(hp);
            *reinterpret_cast<bf16x8*>(&xh[8]) = *reinterpret_cast<const bf16x8*>(hp + 8);
            *reinterpret_cast<bf16x8*>(&xl[0]) = *reinterpret_cast<const bf16x8*>(lp);
            *reinterpret_cast<bf16x8*>(&xl[8]) = *reinterpret_cast<const bf16x8*>(lp + 8);
        }
        {
            float wv[16];
#pragma unroll
            for (int q = 0; q < 4; ++q) {
                float4 b = *reinterpret_cast<const float4*>(Wp + k0 + q * 4);
                wv[q*4+0]=b.x; wv[q*4+1]=b.y; wv[q*4+2]=b.z; wv[q*4+3]=b.w;
            }
#pragma unroll
            for (int j = 0; j < 16; ++j) wh[j] = (short)f32_to_bf16_rn(wv[j]);
        }

        __syncthreads();    // prev-iter LDS reads done
        const int wbase = sr * LDKg + sc;
        *reinterpret_cast<bf16x8*>(&Ah[wbase])     = *reinterpret_cast<bf16x8*>(&xh[0]);
        *reinterpret_cast<bf16x8*>(&Ah[wbase + 8]) = *reinterpret_cast<bf16x8*>(&xh[8]);
        *reinterpret_cast<bf16x8*>(&Al[wbase])     = *reinterpret_cast<bf16x8*>(&xl[0]);
        *reinterpret_cast<bf16x8*>(&Al[wbase + 8]) = *reinterpret_cast<bf16x8*>(&xl[8]);
        *reinterpret_cast<bf16x8*>(&Bh[wbase])     = *reinterpret_cast<bf16x8*>(&wh[0]);
        *reinterpret_cast<bf16x8*>(&Bh[wbase + 8]) = *reinterpret_cast<bf16x8*>(&wh[8]);
        __syncthreads();

        bf16x8 fah[4], fal[4], fbh[4];
#pragma unroll
        for (int mi = 0; mi < 4; ++mi) {
            const int ra = (wm + mi * 16 + fr) * LDKg + kb;
            fah[mi] = *reinterpret_cast<const bf16x8*>(&Ah[ra]);
            fal[mi] = *reinterpret_cast<const bf16x8*>(&Al[ra]);
        }
#pragma unroll
        for (int ni = 0; ni < 4; ++ni) {
            const int rb = (wn + ni * 16 + fr) * LDKg + kb;
            fbh[ni] = *reinterpret_cast<const bf16x8*>(&Bh[rb]);
        }

#pragma unroll
        for (int mi = 0; mi < 4; ++mi)
#pragma unroll
            for (int ni = 0; ni < 4; ++ni) {
                acc[mi][ni] = __builtin_amdgcn_mfma_f32_16x16x32_bf16(
                    fah[mi], fbh[ni], acc[mi][ni], 0, 0, 0);
                acc[mi][ni] = __builtin_amdgcn_mfma_f32_16x16x32_bf16(
                    fal[mi], fbh[ni], acc[mi][ni], 0, 0, 0);
            }
    }

    // ---- epilogue: C/D layout col=lane&15, row=(lane>>4)*4+r ----
    const int fq = lane >> 4;
    if (OMODE == 2) {
        // row bias (swapped GEMM: rows = output features)
#pragma unroll
        for (int mi = 0; mi < 4; ++mi) {
#pragma unroll
            for (int r = 0; r < 4; ++r) {
                const int row = bm + wm + mi * 16 + fq * 4 + r;
                const float bvr = bias[row];
#pragma unroll
                for (int ni = 0; ni < 4; ++ni) {
                    const int col = bn + wn + ni * 16 + fr;
                    outB[(size_t)row * N + col] = f32_to_bf16_rn(acc[mi][ni][r] + bvr);
                }
            }
        }
    } else {
        float bv[4];
#pragma unroll
        for (int ni = 0; ni < 4; ++ni) bv[ni] = bias[bn + wn + ni * 16 + fr];
#pragma unroll
        for (int mi = 0; mi < 4; ++mi)
#pragma unroll
            for (int ni = 0; ni < 4; ++ni) {
                const size_t rowb = (size_t)(bm + wm + mi * 16 + fq * 4);
                const int col = bn + wn + ni * 16 + fr;
#pragma unroll
                for (int r = 0; r < 4; ++r) {
                    float v = acc[mi][ni][r] + bv[ni];
                    if (OMODE == 0) outF[(rowb + r) * N + col] = v;
                    else            outB[(rowb + r) * N + col] = f32_to_bf16_rn(v);
                }
            }
    }
}

// ---------------------------------------------------------------------------
// Flash attention, bf16 MFMA. One block = (b, h, 128-row Q tile); 4 waves,
// wave w owns q-rows [w*32, w*32+32). KVBLK=64.
// K LDS: [k][72] rows. V comes pre-transposed from global ([h*64+d][token])
// so V LDS is [d][72] rows via plain b128 writes (no scatter, no swizzle).
// Softmax in exp2 domain; T13 defer-max (THR=8); output written pre-split
// (hi/lo bf16) for the O-GEMM.
// ---------------------------------------------------------------------------
#define QBLK 128
#define KVB  64
#define LDA  72

__global__ __launch_bounds__(256) void flash_attn_bf16(
    const ushort_t* __restrict__ Qb, const ushort_t* __restrict__ Kb,
    const ushort_t* __restrict__ Vtg, const int* __restrict__ mask,
    ushort_t* __restrict__ Xhi, ushort_t* __restrict__ Xlo)
{
    __shared__ __align__(16) ushort_t Ks[KVB * LDA];
    __shared__ __align__(16) ushort_t Vt[HDIM * LDA];
    __shared__ __align__(16) ushort_t Ps[QBLK * LDA];

    const int b  = blockIdx.y >> 4;
    const int h  = blockIdx.y & 15;
    const int q0 = blockIdx.x * QBLK;
    const int tid  = threadIdx.x;
    const int lane = tid & 63;
    const int w    = tid >> 6;
    const int fr = lane & 15;
    const int fq = lane >> 4;

    const size_t bS = (size_t)b * S_LEN;
    const int hc = h * HDIM;

    // Q fragments in registers
    bf16x8 qf[2][2];
#pragma unroll
    for (int mt = 0; mt < 2; ++mt)
#pragma unroll
        for (int c = 0; c < 2; ++c)
            qf[mt][c] = *reinterpret_cast<const bf16x8*>(
                &Qb[(bS + q0 + w * 32 + mt * 16 + fr) * HID_C + hc + c * 32 + fq * 8]);

    f32x4 OV[2][4];
    float m_[8], l_[8];
#pragma unroll
    for (int mt = 0; mt < 2; ++mt)
#pragma unroll
        for (int dt = 0; dt < 4; ++dt)
#pragma unroll
            for (int r = 0; r < 4; ++r) OV[mt][dt][r] = 0.f;
#pragma unroll
    for (int i = 0; i < 8; ++i) { m_[i] = -1e30f; l_[i] = 0.f; }

    // K stager: row = tid>>2 (0..63), seg = tid&3.  V stager: d-row likewise.
    const int sr  = tid >> 2;
    const int seg = tid & 3;

    for (int t = 0; t < S_LEN; t += KVB) {
        // ---- global loads (issued before barrier) ----
        const ushort_t* kp = &Kb[(bS + t + sr) * HID_C + hc + seg * 16];
        const ushort_t* vp = &Vtg[(size_t)(hc + sr) * (4 * S_LEN) + bS + t + seg * 16];
        bf16x8 kv0 = *reinterpret_cast<const bf16x8*>(kp);
        bf16x8 kv1 = *reinterpret_cast<const bf16x8*>(kp + 8);
        bf16x8 vv0 = *reinterpret_cast<const bf16x8*>(vp);
        bf16x8 vv1 = *reinterpret_cast<const bf16x8*>(vp + 8);

        __syncthreads();   // prev-iter LDS reads done

        *reinterpret_cast<bf16x8*>(&Ks[sr * LDA + seg * 16])     = kv0;
        *reinterpret_cast<bf16x8*>(&Ks[sr * LDA + seg * 16 + 8]) = kv1;
        *reinterpret_cast<bf16x8*>(&Vt[sr * LDA + seg * 16])     = vv0;
        *reinterpret_cast<bf16x8*>(&Vt[sr * LDA + seg * 16 + 8]) = vv1;
        __syncthreads();

        int mk[4];
#pragma unroll
        for (int nt = 0; nt < 4; ++nt) mk[nt] = mask[bS + t + nt * 16 + fr];

        // ---- QK^T ----
        f32x4 S[2][4];
#pragma unroll
        for (int mt = 0; mt < 2; ++mt)
#pragma unroll
            for (int nt = 0; nt < 4; ++nt)
#pragma unroll
                for (int r = 0; r < 4; ++r) S[mt][nt][r] = 0.f;

#pragma unroll
        for (int nt = 0; nt < 4; ++nt)
#pragma unroll
            for (int c = 0; c < 2; ++c) {
                bf16x8 kf = *reinterpret_cast<const bf16x8*>(
                    &Ks[(nt * 16 + fr) * LDA + c * 32 + fq * 8]);
#pragma unroll
                for (int mt = 0; mt < 2; ++mt)
                    S[mt][nt] = __builtin_amdgcn_mfma_f32_16x16x32_bf16(
                        qf[mt][c], kf, S[mt][nt], 0, 0, 0);
            }

        // ---- scale (exp2 domain) + mask ----
        const float sc2 = 0.125f * LOG2E;
#pragma unroll
        for (int mt = 0; mt < 2; ++mt)
#pragma unroll
            for (int nt = 0; nt < 4; ++nt)
#pragma unroll
                for (int r = 0; r < 4; ++r)
                    S[mt][nt][r] = (mk[nt] != 0) ? S[mt][nt][r] * sc2 : -1e30f;

        // ---- row max + defer-max check ----
        float mx[2][4];
        int okl = 1;
#pragma unroll
        for (int mt = 0; mt < 2; ++mt)
#pragma unroll
            for (int r = 0; r < 4; ++r) {
                float v = fmaxf(fmaxf(S[mt][0][r], S[mt][1][r]),
                                fmaxf(S[mt][2][r], S[mt][3][r]));
                v = fmaxf(v, __shfl_xor(v, 1));
                v = fmaxf(v, __shfl_xor(v, 2));
                v = fmaxf(v, __shfl_xor(v, 4));
                v = fmaxf(v, __shfl_xor(v, 8));
                mx[mt][r] = v;
                okl &= (v <= m_[mt * 4 + r] + 8.f);
            }
        if (!__all(okl)) {
#pragma unroll
            for (int mt = 0; mt < 2; ++mt)
#pragma unroll
                for (int r = 0; r < 4; ++r) {
                    const int qi = mt * 4 + r;
                    float mn = fmaxf(m_[qi], mx[mt][r]);
                    float corr = exp2f(m_[qi] - mn);
                    m_[qi] = mn;
                    l_[qi] *= corr;
#pragma unroll
                    for (int dt = 0; dt < 4; ++dt) OV[mt][dt][r] *= corr;
                }
        }

        // ---- P = exp2(S - m), row-sum, stage P ----
#pragma unroll
        for (int mt = 0; mt < 2; ++mt)
#pragma unroll
            for (int r = 0; r < 4; ++r) {
                const int qi = mt * 4 + r;
                float ls = 0.f;
#pragma unroll
                for (int nt = 0; nt < 4; ++nt) {
                    float p = exp2f(S[mt][nt][r] - m_[qi]);
                    Ps[(w * 32 + mt * 16 + fq * 4 + r) * LDA + nt * 16 + fr] =
                        f32_to_bf16_rn(p);
                    ls += p;
                }
                ls += __shfl_xor(ls, 1);
                ls += __shfl_xor(ls, 2);
                ls += __shfl_xor(ls, 4);
                ls += __shfl_xor(ls, 8);
                l_[qi] += ls;
            }
        // wave-private Ps region: writer == reader wave.

        // ---- PV ----
        bf16x8 pf[2][2];
#pragma unroll
        for (int mt = 0; mt < 2; ++mt)
#pragma unroll
            for (int c = 0; c < 2; ++c)
                pf[mt][c] = *reinterpret_cast<const bf16x8*>(
                    &Ps[(w * 32 + mt * 16 + fr) * LDA + c * 32 + fq * 8]);

#pragma unroll
        for (int dt = 0; dt < 4; ++dt)
#pragma unroll
            for (int c = 0; c < 2; ++c) {
                bf16x8 vf = *reinterpret_cast<const bf16x8*>(
                    &Vt[(dt * 16 + fr) * LDA + c * 32 + fq * 8]);
#pragma unroll
                for (int mt = 0; mt < 2; ++mt)
                    OV[mt][dt] = __builtin_amdgcn_mfma_f32_16x16x32_bf16(
                        pf[mt][c], vf, OV[mt][dt], 0, 0, 0);
            }
    }

    // ---- epilogue: x = OV/l, written pre-split hi/lo bf16 ----
#pragma unroll
    for (int mt = 0; mt < 2; ++mt)
#pragma unroll
        for (int r = 0; r < 4; ++r) {
            const float inv = 1.f / l_[mt * 4 + r];
            const size_t row = bS + q0 + w * 32 + mt * 16 + fq * 4 + r;
#pragma unroll
            for (int dt = 0; dt < 4; ++dt) {
                float v = OV[mt][dt][r] * inv;
                unsigned int u = __float_as_uint(v);
                unsigned short hi = (unsigned short)(u >> 16);   // trunc hi
                float res = v - __uint_as_float(u & 0xFFFF0000u);
                Xhi[row * HID_C + hc + dt * 16 + fr] = hi;
                Xlo[row * HID_C + hc + dt * 16 + fr] = f32_to_bf16_rn(res);
            }
        }
}

// ---------------------------------------------------------------------------
extern "C" void kernel_launch(void* const* d_in, const int* in_sizes, int n_in,
                              void* d_out, int out_size, void* d_ws, size_t ws_size,
                              hipStream_t stream) {
    const float* query = (const float*)d_in[0];
    const float* key   = (const float*)d_in[1];
    const float* value = (const float*)d_in[2];
    const int*   mask  = (const int*)d_in[3];
    const float* Wq = (const float*)d_in[4];
    const float* bq = (const float*)d_in[5];
    const float* Wk = (const float*)d_in[6];
    const float* bk = (const float*)d_in[7];
    const float* Wv = (const float*)d_in[8];
    const float* bv = (const float*)d_in[9];
    const float* Wo = (const float*)d_in[10];
    const float* bo = (const float*)d_in[11];
    float* out = (float*)d_out;

    const int B = 4, M = B * S_LEN;          // 8192
    const size_t seg = (size_t)M * HID_C;

    ushort_t* Qb  = (ushort_t*)d_ws;         // 16MB each
    ushort_t* Kb  = Qb + seg;
    ushort_t* Vtg = Kb + seg;                // V^T: [1024 feat][8192 tok]
    ushort_t* Xhi = Vtg + seg;
    ushort_t* Xlo = Xhi + seg;               // total 80MB

    dim3 gg(HID_C / BN, M / BM);             // (8, 64)
    gemm_xwt_bias_mfma<1, 0><<<gg, 256, 0, stream>>>(
        query, nullptr, nullptr, Wq, bq, nullptr, Qb, M, HID_C, HID_C);
    gemm_xwt_bias_mfma<1, 0><<<gg, 256, 0, stream>>>(
        key,   nullptr, nullptr, Wk, bk, nullptr, Kb, M, HID_C, HID_C);
    // V^T: out[feat][token] = Wv @ value^T  (swapped roles, row bias)
    dim3 gv(M / BN, HID_C / BM);             // (64, 8)
    gemm_xwt_bias_mfma<2, 0><<<gv, 256, 0, stream>>>(
        Wv, nullptr, nullptr, value, bv, nullptr, Vtg, HID_C, M, HID_C);

    dim3 ga(S_LEN / QBLK, B * NHEADS);       // (16, 64)
    flash_attn_bf16<<<ga, 256, 0, stream>>>(Qb, Kb, Vtg, mask, Xhi, Xlo);

    gemm_xwt_bias_mfma<0, 1><<<gg, 256, 0, stream>>>(
        nullptr, Xhi, Xlo, Wo, bo, out, nullptr, M, HID_C, HID_C);
}